// Round 7
// baseline (6800.474 us; speedup 1.0000x reference)
//
#include <hip/hip_runtime.h>

typedef unsigned int  u32;
typedef unsigned short u16;
typedef float v2f __attribute__((ext_vector_type(2)));
typedef __attribute__((ext_vector_type(8))) short bfv8;   // 8 bf16 = 4 VGPR
typedef __attribute__((ext_vector_type(4))) float f32x4;

// B=8, NS=80, NN=81, H=256, L=2, STEPS=8, VOCAB=30000
#define ROWS 648          // B*NN
#define KROWS 52488       // 8*81*81 skip rows

__device__ __forceinline__ float sigf(float x){ return 1.0f/(1.0f+__expf(-x)); }
__device__ __forceinline__ float tanh_fast(float x){
  float e = __expf(-2.0f*fabsf(x));
  float r = (1.0f-e)/(1.0f+e);
  return copysignf(r,x);
}
__device__ __forceinline__ u16 f2bf(float f){        // RTNE f32->bf16
  u32 u = __float_as_uint(f);
  u += 0x7FFFu + ((u>>16)&1u);
  return (u16)(u>>16);
}
__device__ __forceinline__ u32 packbf2(float lo, float hi){
  return (u32)f2bf(lo) | ((u32)f2bf(hi)<<16);
}
__device__ __forceinline__ float bf2f(u16 v){ return __uint_as_float(((u32)v)<<16); }

#define AG __HIP_MEMORY_SCOPE_AGENT
__device__ __forceinline__ void ast(float* p, float v){
  __hip_atomic_store(p, v, __ATOMIC_RELAXED, AG);
}
__device__ __forceinline__ float ald(const float* p){
  return __hip_atomic_load(p, __ATOMIC_RELAXED, AG);
}

// ---------------- weight packing ----------------------------------------
// MFMA B-fragment pack, concat two [256 x 1024] sources along K (N=1024).
// frag (tile t, kstep ks): lane l holds B[k = ks*32+(l>>4)*8+e][col = t*16+(l&15)]
__global__ void pack_mfma(const float* __restrict__ A, const float* __restrict__ Bm,
                          u32* __restrict__ dst, int K){
  int id = blockIdx.x*256 + threadIdx.x;
  int KS = K >> 5;
  int tot = 64*KS*64*4;
  if (id >= tot) return;
  int e2 = id & 3;
  int l  = (id >> 2) & 63;
  int rest = id >> 8;
  int ks = rest % KS;
  int t  = rest / KS;
  int k  = ks*32 + (l>>4)*8 + e2*2;
  int col = t*16 + (l&15);
  float v0 = (k   < 256) ? A[k*1024 + col]       : Bm[(k-256)*1024 + col];
  float v1 = (k+1 < 256) ? A[(k+1)*1024 + col]   : Bm[(k+1-256)*1024 + col];
  dst[id] = packbf2(v0, v1);
}

// Generic MFMA B-frag pack from one [K x (NT*16)] row-major matrix.
__global__ void pack_w(const float* __restrict__ src, u32* __restrict__ dst,
                       int K, int NT){
  int id = blockIdx.x*256 + threadIdx.x;
  int KS = K >> 5;
  int tot = NT*KS*64*4;
  if (id >= tot) return;
  int e2 = id & 3;
  int l  = (id >> 2) & 63;
  int rest = id >> 8;
  int ks = rest % KS;
  int t  = rest / KS;
  int k  = ks*32 + (l>>4)*8 + e2*2;
  int col = t*16 + (l&15);
  int ld = NT*16;
  dst[id] = packbf2(src[k*ld + col], src[(k+1)*ld + col]);
}

__global__ void k_init_p(float* __restrict__ p0){
  int i = blockIdx.x*256 + threadIdx.x;
  if (i < ROWS) p0[i] = ((i % 81)==0) ? 1.0f : 0.0f;
}

// ---------------- K1: statement embedder + X0 precompute ----------------
__global__ __launch_bounds__(512) void k_stmt_x0(
    const float* __restrict__ ne, const float* __restrict__ stWx, const float* __restrict__ stb,
    const float* __restrict__ skWx, const float* __restrict__ skb, float4* __restrict__ X0){
  __shared__ float xv[2][256];
  __shared__ float hv[2][256];
  int r = threadIdx.x >> 8, j = threadIdx.x & 255;
  int bn = blockIdx.x*2 + r;                    // 0..639
  xv[r][j] = ne[bn*256 + j];
  __syncthreads();
  float a0=stb[j], a2=stb[512+j], a3=stb[768+j];
  for (int k=0;k<256;k++){
    float x = xv[r][k];
    const float* w = stWx + k*1024;
    a0 = fmaf(x, w[j], a0); a2 = fmaf(x, w[512+j], a2); a3 = fmaf(x, w[768+j], a3);
  }
  float c = sigf(a0)*tanh_fast(a2);
  float h = sigf(a3)*tanh_fast(c);
  hv[r][j] = h;
  __syncthreads();
  a0=stb[1024+j]; a2=stb[1536+j]; a3=stb[1792+j];
  const float* W1 = stWx + 256*1024;
  for (int k=0;k<256;k++){
    float x = hv[r][k];
    const float* w = W1 + k*1024;
    a0 = fmaf(x, w[j], a0); a2 = fmaf(x, w[512+j], a2); a3 = fmaf(x, w[768+j], a3);
  }
  c = sigf(a0)*tanh_fast(a2);
  h = sigf(a3)*tanh_fast(c);
  __syncthreads();
  xv[r][j] = h;           // stmt row
  __syncthreads();
  float b0=skb[j], b1g=skb[256+j], b2=skb[512+j], b3=skb[768+j];
  for (int k=0;k<256;k++){
    float x = xv[r][k];
    const float* w = skWx + k*1024;
    b0 = fmaf(x, w[j], b0);     b1g = fmaf(x, w[256+j], b1g);
    b2 = fmaf(x, w[512+j], b2); b3 = fmaf(x, w[768+j], b3);
  }
  X0[bn*256 + j] = make_float4(b0,b1g,b2,b3);
}

// ---------------- K3: skip-encoder chains (4-block j-split, paired) ------
// 160 blocks = 40 groups x 4 quarters. Group g handles chains s=g (rows 0-7)
// and s=g+40 (rows 8-15), one batch per row. Quarter q owns j in
// [64q,64q+64): streams 1/4 of the weights and computes complete cells for
// its j's. Cross-block per step: h0_raw after L0 cell (flagA), h1_raw + LN
// partial stats after L1 cell (flagB). ex_h0 double-buffered by step parity
// (only overwrite race); ex_h1/ex_st single-buffered (protected by flagA of
// the next step). All data via agent-scope atomics; flags release/acquire.
// All 160 blocks co-resident (<=256 CUs, LDS>80KB forces 1 block/CU).
#define RS0 264   // A0 row stride (u16), K=256 (+8 pad)
#define RS1 520   // A1 row stride (u16), K=512 (+8 pad)
#define PSG 66    // part gate stride (f32)
__global__ __launch_bounds__(1024) void k_skip_chains(
    const float4* __restrict__ X0,
    const uint4* __restrict__ W0m, const uint4* __restrict__ W1m,
    const float* __restrict__ skb, const float* __restrict__ lnS, const float* __restrict__ lnB,
    float* __restrict__ skip,
    float* __restrict__ ex_h0,   // [2][40][4][16*64]
    float* __restrict__ ex_h1,   // [40][4][16*64]
    float* __restrict__ ex_st,   // [40][4][32]
    int* __restrict__ flagA, int* __restrict__ flagB){
  int blk = blockIdx.x;
  int g = (blk & 7) + ((blk >> 5) << 3);  // 4 blocks of a group share blk%8 (same XCD if %8 mapping)
  int q = (blk >> 3) & 3;
  int tid = threadIdx.x;
  int w = tid >> 6, lane = tid & 63;
  int l15 = lane & 15, l4 = lane >> 4;
  __shared__ u16 A0h[16*RS0], A0l[16*RS0];
  __shared__ u16 A1h[16*RS1], A1l[16*RS1];
  __shared__ float part[16*4*PSG];
  __shared__ float lds_pad[4096];       // total 83456B -> 1 block/CU
  if (tid == 0) lds_pad[0] = 0.f;       // keep alive
  for (int i=tid;i<16*RS0;i+=1024){ A0h[i]=0; A0l[i]=0; }
  for (int i=tid;i<16*RS1;i+=1024){ A1h[i]=0; A1l[i]=0; }
  // matvec role: wave w -> tile T (gate = w>>2, j-subtile = w&3)
  const int T = ((w>>2)<<4) + (q<<2) + (w&3);
  const int gate = w>>2, jj16 = w&3; (void)gate; (void)jj16;
  // cell role: row r = w (one cell per thread at (r, jg))
  const int r = w;
  const int b = r & 7, ch = r >> 3;
  const int sc = g + 40*ch;
  const int jg = (q<<6) + lane;
  const float s1b0=skb[1024+jg], s1b1=skb[1280+jg], s1b2=skb[1536+jg], s1b3=skb[1792+jg];
  const float lSc0=lnS[jg], lBc0=lnB[jg], lSc2=lnS[512+jg], lBc2=lnB[512+jg];
  float c0=0.f, c1=0.f;
  const int aoff0 = l15*RS0 + l4*8;
  const int aoff1 = l15*RS1 + l4*8;
  const int fbase = g*4;
  __syncthreads();
  for (int idx=g; idx<80; idx++){
    int t = idx - g + 1;
    int par = (idx - g) & 1;
    bool act = (idx >= sc);
    // ---- phase 1: L0 matvec (A0 = h0_ln, K=256)
    f32x4 acc = {0,0,0,0};
    #pragma unroll
    for (int ks=0; ks<8; ks++){
      bfv8 ah = *(const bfv8*)&A0h[aoff0 + ks*32];
      bfv8 al = *(const bfv8*)&A0l[aoff0 + ks*32];
      uint4 bw = W0m[(T*8 + ks)*64 + lane];
      bfv8 v = __builtin_bit_cast(bfv8, bw);
      acc = __builtin_amdgcn_mfma_f32_16x16x32_bf16(ah, v, acc, 0,0,0);
      acc = __builtin_amdgcn_mfma_f32_16x16x32_bf16(al, v, acc, 0,0,0);
    }
    {
      int r0 = l4*4;
      #pragma unroll
      for (int q4=0;q4<4;q4++)
        part[((r0+q4)*4 + (w>>2))*PSG + ((w&3)<<4) + l15] = acc[q4];
    }
    __syncthreads();
    // ---- phase 2: L0 cell (own j), publish h0_raw
    float h0 = 0.f;
    {
      float4 gx = X0[(b*80 + idx)*256 + jg];
      float a0 = gx.x + part[(r*4+0)*PSG + lane];
      float a1 = gx.y + part[(r*4+1)*PSG + lane];
      float a2 = gx.z + part[(r*4+2)*PSG + lane];
      float a3 = gx.w + part[(r*4+3)*PSG + lane];
      if (act){
        float ii=sigf(a0), ff=sigf(a1), gg=tanh_fast(a2), oo=sigf(a3);
        c0 = ff*c0 + ii*gg;
        h0 = oo*tanh_fast(c0);
      }
    }
    ast(&ex_h0[((par*40+g)*4 + q)*1024 + r*64 + lane], h0);
    __threadfence();
    __syncthreads();
    if (tid == 0) __hip_atomic_store(&flagA[fbase+q], t, __ATOMIC_RELEASE, AG);
    if (tid < 4){
      while (__hip_atomic_load(&flagA[fbase+tid], __ATOMIC_ACQUIRE, AG) < t) {}
    }
    __syncthreads();
    // ---- phase 3: rebuild A1 first half = h0_raw (all j), hi/lo bf16
    {
      int j0 = lane*4, qq = j0>>6, jo = j0&63;
      const float* src = &ex_h0[((par*40+g)*4 + qq)*1024 + r*64 + jo];
      float v0=ald(src+0), v1=ald(src+1), v2=ald(src+2), v3=ald(src+3);
      ushort4 hi4, lo4;
      hi4.x=f2bf(v0); lo4.x=f2bf(v0-bf2f(hi4.x));
      hi4.y=f2bf(v1); lo4.y=f2bf(v1-bf2f(hi4.y));
      hi4.z=f2bf(v2); lo4.z=f2bf(v2-bf2f(hi4.z));
      hi4.w=f2bf(v3); lo4.w=f2bf(v3-bf2f(hi4.w));
      *(ushort4*)&A1h[r*RS1 + j0] = hi4;
      *(ushort4*)&A1l[r*RS1 + j0] = lo4;
    }
    __syncthreads();
    // ---- phase 4: L1 matvec (A1 = [h0_raw | h1_ln], K=512)
    acc = (f32x4){0,0,0,0};
    #pragma unroll
    for (int ks=0; ks<16; ks++){
      bfv8 ah = *(const bfv8*)&A1h[aoff1 + ks*32];
      bfv8 al = *(const bfv8*)&A1l[aoff1 + ks*32];
      uint4 bw = W1m[(T*16 + ks)*64 + lane];
      bfv8 v = __builtin_bit_cast(bfv8, bw);
      acc = __builtin_amdgcn_mfma_f32_16x16x32_bf16(ah, v, acc, 0,0,0);
      acc = __builtin_amdgcn_mfma_f32_16x16x32_bf16(al, v, acc, 0,0,0);
    }
    {
      int r0 = l4*4;
      #pragma unroll
      for (int q4=0;q4<4;q4++)
        part[((r0+q4)*4 + (w>>2))*PSG + ((w&3)<<4) + l15] = acc[q4];
    }
    __syncthreads();
    // ---- phase 5: L1 cell (own j), skip write, publish h1 + partial stats
    float h1 = 0.f;
    {
      float a0 = s1b0 + part[(r*4+0)*PSG + lane];
      float a1 = s1b1 + part[(r*4+1)*PSG + lane];
      float a2 = s1b2 + part[(r*4+2)*PSG + lane];
      float a3 = s1b3 + part[(r*4+3)*PSG + lane];
      if (act){
        float ii=sigf(a0), ff=sigf(a1), gg=tanh_fast(a2), oo=sigf(a3);
        c1 = ff*c1 + ii*gg;
        h1 = oo*tanh_fast(c1);
        skip[((b*81 + sc)*81 + (idx+1))*256 + jg] = h1;
      }
    }
    ast(&ex_h1[(g*4 + q)*1024 + r*64 + lane], h1);
    {
      float sm = c0 + h0 + c1 + h1;
      float sq = c0*c0 + h0*h0 + c1*c1 + h1*h1;
      #pragma unroll
      for (int off=32; off; off>>=1){ sm += __shfl_xor(sm, off); sq += __shfl_xor(sq, off); }
      if (lane == 0){
        ast(&ex_st[(g*4 + q)*32 + r*2],     sm);
        ast(&ex_st[(g*4 + q)*32 + r*2 + 1], sq);
      }
    }
    __threadfence();
    __syncthreads();
    if (tid == 0) __hip_atomic_store(&flagB[fbase+q], t, __ATOMIC_RELEASE, AG);
    if (tid < 4){
      while (__hip_atomic_load(&flagB[fbase+tid], __ATOMIC_ACQUIRE, AG) < t) {}
    }
    __syncthreads();
    // ---- phase 6: full LN stats (per row = wave), LN own c's,
    //      rebuild A0 (h0_ln) and A1 second half (h1_ln) for all j
    float pv = 0.f;
    if (lane < 8){
      int qq2 = lane & 3, which = lane >> 2;
      pv = ald(&ex_st[(g*4 + qq2)*32 + r*2 + which]);
    }
    float sm4 = __shfl(pv,0)+__shfl(pv,1)+__shfl(pv,2)+__shfl(pv,3);
    float sq4 = __shfl(pv,4)+__shfl(pv,5)+__shfl(pv,6)+__shfl(pv,7);
    float mu = sm4 * (1.0f/1024.0f);
    float var = sq4 * (1.0f/1024.0f) - mu*mu;
    float rstd = rsqrtf(var + 1e-6f);
    if (act){
      c0 = (c0 - mu)*rstd*lSc0 + lBc0;
      c1 = (c1 - mu)*rstd*lSc2 + lBc2;
    }
    {
      int j0 = lane*4, qq = j0>>6, jo = j0&63;
      const float* s0 = &ex_h0[((par*40+g)*4 + qq)*1024 + r*64 + jo];
      const float* s1 = &ex_h1[(g*4 + qq)*1024 + r*64 + jo];
      float h0v[4], h1v[4];
      h0v[0]=ald(s0+0); h0v[1]=ald(s0+1); h0v[2]=ald(s0+2); h0v[3]=ald(s0+3);
      h1v[0]=ald(s1+0); h1v[1]=ald(s1+1); h1v[2]=ald(s1+2); h1v[3]=ald(s1+3);
      ushort4 h0h, h0lo, h1h, h1lo;
      u16* ph0h = (u16*)&h0h; u16* ph0l = (u16*)&h0lo;
      u16* ph1h = (u16*)&h1h; u16* ph1l = (u16*)&h1lo;
      #pragma unroll
      for (int k=0;k<4;k++){
        int jt = j0 + k;
        float h0ln = act ? (h0v[k]-mu)*rstd*lnS[256+jt] + lnB[256+jt] : 0.f;
        float h1ln = act ? (h1v[k]-mu)*rstd*lnS[768+jt] + lnB[768+jt] : 0.f;
        u16 hi = f2bf(h0ln); ph0h[k]=hi; ph0l[k]=f2bf(h0ln-bf2f(hi));
        hi = f2bf(h1ln); ph1h[k]=hi; ph1l[k]=f2bf(h1ln-bf2f(hi));
      }
      *(ushort4*)&A0h[r*RS0 + j0] = h0h;
      *(ushort4*)&A0l[r*RS0 + j0] = h0lo;
      *(ushort4*)&A1h[r*RS1 + 256 + j0] = h1h;
      *(ushort4*)&A1l[r*RS1 + 256 + j0] = h1lo;
    }
    __syncthreads();
  }
}

// ---------------- K4: keys = skip @ ws + bs  (MFMA, bf16 out) ------------
__global__ __launch_bounds__(1024) void k_keys(const float* __restrict__ skip,
    const uint4* __restrict__ WSm, const float* __restrict__ bs, u16* __restrict__ keys){
  int rows0 = blockIdx.x*16;
  int tid = threadIdx.x;
  int w = tid >> 6, lane = tid & 63;
  int l15 = lane & 15, l4 = lane >> 4;
  __shared__ u16 Ah[16*RS0], Al[16*RS0];
  __shared__ u16 kbuf[16*256];
  {
    int grow = rows0 + w;
    float4 v = {0,0,0,0};
    if (grow < KROWS) v = ((const float4*)skip)[grow*64 + lane];
    ushort4 hi4, lo4;
    hi4.x=f2bf(v.x); lo4.x=f2bf(v.x-bf2f(hi4.x));
    hi4.y=f2bf(v.y); lo4.y=f2bf(v.y-bf2f(hi4.y));
    hi4.z=f2bf(v.z); lo4.z=f2bf(v.z-bf2f(hi4.z));
    hi4.w=f2bf(v.w); lo4.w=f2bf(v.w-bf2f(hi4.w));
    *(ushort4*)&Ah[w*RS0 + lane*4] = hi4;
    *(ushort4*)&Al[w*RS0 + lane*4] = lo4;
  }
  __syncthreads();
  const int aoff = l15*RS0 + l4*8;
  f32x4 acc = {0,0,0,0};
  #pragma unroll
  for (int ks=0; ks<8; ks++){
    bfv8 ah = *(const bfv8*)&Ah[aoff + ks*32];
    bfv8 al = *(const bfv8*)&Al[aoff + ks*32];
    uint4 b = WSm[(w*8 + ks)*64 + lane];
    bfv8 v = __builtin_bit_cast(bfv8, b);
    acc = __builtin_amdgcn_mfma_f32_16x16x32_bf16(ah, v, acc, 0,0,0);
    acc = __builtin_amdgcn_mfma_f32_16x16x32_bf16(al, v, acc, 0,0,0);
  }
  float bsv = bs[w*16 + l15];
  #pragma unroll
  for (int q=0;q<4;q++)
    kbuf[(l4*4+q)*256 + w*16 + l15] = f2bf(acc[q] + bsv);
  __syncthreads();
  int nval = KROWS - rows0; if (nval > 16) nval = 16;
  int words = nval*128;
  u32* kout = (u32*)keys + (size_t)rows0*128;
  const u32* kin = (const u32*)kbuf;
  for (int i=tid; i<words; i+=1024) kout[i] = kin[i];
}

// ---------------- Kb: logits -> softmax -> t (q precomputed) -------------
__global__ __launch_bounds__(256) void k_attn(
    const float* __restrict__ qb, const u16* __restrict__ keys,
    const float* __restrict__ w1, const float* __restrict__ pcur,
    float* __restrict__ t, int mode){
  int bn = blockIdx.x; int n = bn % 81;
  int tid = threadIdx.x;
  float pv = pcur[bn];
  if (pv == 0.0f){
    if (tid < 81) t[bn*81 + tid] = 0.0f;
    return;
  }
  if (mode == 0){ if (tid < 81) t[bn*81 + tid] = (tid==1)  ? pv : 0.0f; return; }
  if (mode == 2){ if (tid < 81) t[bn*81 + tid] = (tid==80) ? pv : 0.0f; return; }
  __shared__ float qv[256];
  __shared__ float lg[81];
  qv[tid] = qb[bn*256 + tid];
  if (tid < 81) lg[tid] = -3e38f;
  __syncthreads();
  int lane = tid & 63, wv = tid >> 6;
  float w1v0 = w1[lane], w1v1 = w1[64+lane], w1v2 = w1[128+lane], w1v3 = w1[192+lane];
  for (int m = wv; m < 81; m += 4){
    if (!(m>n || m==80)) continue;
    const u16* kr = keys + (bn*81+m)*256;
    float acc;
    acc  = tanh_fast(qv[lane]     + bf2f(kr[lane]))     * w1v0;
    acc += tanh_fast(qv[64+lane]  + bf2f(kr[64+lane]))  * w1v1;
    acc += tanh_fast(qv[128+lane] + bf2f(kr[128+lane])) * w1v2;
    acc += tanh_fast(qv[192+lane] + bf2f(kr[192+lane])) * w1v3;
    #pragma unroll
    for (int off=32; off; off>>=1) acc += __shfl_xor(acc, off);
    if (lane==0) lg[m] = acc;      // b1 omitted: softmax-invariant
  }
  __syncthreads();
  if (tid < 64){
    float v1 = lg[tid];
    float v2 = (tid<17) ? lg[64+tid] : -3e38f;
    float mx = fmaxf(v1, v2);
    #pragma unroll
    for (int off=32; off; off>>=1) mx = fmaxf(mx, __shfl_xor(mx, off));
    float e1 = __expf(v1-mx);
    float e2 = (tid<17) ? __expf(v2-mx) : 0.0f;
    float ssum = e1+e2;
    #pragma unroll
    for (int off=32; off; off>>=1) ssum += __shfl_xor(ssum, off);
    float sc = pv / ssum;
    t[bn*81 + tid] = e1*sc;
    if (tid<17) t[bn*81 + 64+tid] = e2*sc;
  }
}

// ---------------- Kg: gather einsums (x_in + state props + new_p) --------
__global__ __launch_bounds__(256) void k_gather(
    const float* __restrict__ t, const float* __restrict__ skip,
    const float* __restrict__ c0i, const float* __restrict__ h0i,
    const float* __restrict__ c1i, const float* __restrict__ h1i,
    float* __restrict__ xin, float* __restrict__ h0p,
    float* __restrict__ h1p, float* __restrict__ c0p,
    float* __restrict__ c1p, float* __restrict__ pnext){
  int row = blockIdx.x;           // b*81+m
  int b = row / 81, m = row - b*81;
  int tid = threadIdx.x;
  __shared__ float tcol[81];
  if (tid < 81) tcol[tid] = t[(b*81+tid)*81 + m];
  __syncthreads();
  int nlim = (m==80) ? 81 : m;    // t[n,m]==0 for n>=m (unless m==80)
  float ts = 0.f;
  for (int n=0;n<nlim;n++) ts += tcol[n];
  if (tid==0) pnext[row] = ts;
  int o = row*256 + tid;
  if (ts == 0.0f){
    xin[o]=0.f; h0p[o]=0.f; h1p[o]=0.f; c0p[o]=0.f; c1p[o]=0.f;
    return;
  }
  float xa=0.f, c0a=0.f, h0a=0.f, c1a=0.f, h1a=0.f;
  for (int n=0;n<nlim;n++){
    float tv = tcol[n];
    int st = (b*81+n)*256 + tid;
    xa  = fmaf(tv, skip[((b*81+n)*81 + m)*256 + tid], xa);
    c0a = fmaf(tv, c0i[st], c0a);
    h0a = fmaf(tv, h0i[st], h0a);
    c1a = fmaf(tv, c1i[st], c1a);
    h1a = fmaf(tv, h1i[st], h1a);
  }
  float inv = 1.0f/(ts + 1e-7f);
  xin[o]=xa*inv; h0p[o]=h0a*inv; h1p[o]=h1a*inv; c0p[o]=c0a*inv; c1p[o]=c1a*inv;
}

// ---------------- Kx: ex-LSTM step + fused q via MFMA --------------------
#define RSX 1032
#define PSX 1028
__global__ __launch_bounds__(1024) void k_exlstm(
    const float* __restrict__ xin, const float* __restrict__ h0pg,
    const float* __restrict__ h1pg, const float* __restrict__ c0pg,
    const float* __restrict__ c1pg,
    const uint4* __restrict__ WAm, const uint4* __restrict__ WBm,
    const uint4* __restrict__ WKm,
    const float* __restrict__ exb, const float* __restrict__ bk,
    float* __restrict__ c0o, float* __restrict__ h0o,
    float* __restrict__ c1o, float* __restrict__ h1o,
    float* __restrict__ qb){
  int row0 = blockIdx.x*16;
  int tid = threadIdx.x;
  int w = tid >> 6, lane = tid & 63;
  int l15 = lane & 15, l4 = lane >> 4;
  int rp = tid >> 8, j = tid & 255;
  __shared__ float part[16*PSX];
  __shared__ u16 Ah[16*RSX], Al[16*RSX];
  {
    int grow = row0 + w;
    float4 vx = {0,0,0,0}, vh = {0,0,0,0};
    if (grow < ROWS){
      vx = ((const float4*)xin)[grow*64 + lane];
      vh = ((const float4*)h0pg)[grow*64 + lane];
    }
    ushort4 hi4, lo4;
    hi4.x=f2bf(vx.x); lo4.x=f2bf(vx.x-bf2f(hi4.x));
    hi4.y=f2bf(vx.y); lo4.y=f2bf(vx.y-bf2f(hi4.y));
    hi4.z=f2bf(vx.z); lo4.z=f2bf(vx.z-bf2f(hi4.z));
    hi4.w=f2bf(vx.w); lo4.w=f2bf(vx.w-bf2f(hi4.w));
    *(ushort4*)&Ah[w*RSX + lane*4] = hi4;
    *(ushort4*)&Al[w*RSX + lane*4] = lo4;
    hi4.x=f2bf(vh.x); lo4.x=f2bf(vh.x-bf2f(hi4.x));
    hi4.y=f2bf(vh.y); lo4.y=f2bf(vh.y-bf2f(hi4.y));
    hi4.z=f2bf(vh.z); lo4.z=f2bf(vh.z-bf2f(hi4.z));
    hi4.w=f2bf(vh.w); lo4.w=f2bf(vh.w-bf2f(hi4.w));
    *(ushort4*)&Ah[w*RSX + 256 + lane*4] = hi4;
    *(ushort4*)&Al[w*RSX + 256 + lane*4] = lo4;
  }
  __syncthreads();
  const int aoff = l15*RSX + l4*8;
  f32x4 acc0={0,0,0,0}, acc1={0,0,0,0}, acc2={0,0,0,0}, acc3={0,0,0,0};
  #pragma unroll 4
  for (int ks=0; ks<16; ks++){
    bfv8 ah = *(const bfv8*)&Ah[aoff + ks*32];
    bfv8 al = *(const bfv8*)&Al[aoff + ks*32];
    uint4 b0 = WAm[((w*4+0)*16 + ks)*64 + lane];
    uint4 b1 = WAm[((w*4+1)*16 + ks)*64 + lane];
    uint4 b2 = WAm[((w*4+2)*16 + ks)*64 + lane];
    uint4 b3 = WAm[((w*4+3)*16 + ks)*64 + lane];
    bfv8 v0=__builtin_bit_cast(bfv8,b0), v1=__builtin_bit_cast(bfv8,b1);
    bfv8 v2=__builtin_bit_cast(bfv8,b2), v3=__builtin_bit_cast(bfv8,b3);
    acc0=__builtin_amdgcn_mfma_f32_16x16x32_bf16(ah,v0,acc0,0,0,0);
    acc0=__builtin_amdgcn_mfma_f32_16x16x32_bf16(al,v0,acc0,0,0,0);
    acc1=__builtin_amdgcn_mfma_f32_16x16x32_bf16(ah,v1,acc1,0,0,0);
    acc1=__builtin_amdgcn_mfma_f32_16x16x32_bf16(al,v1,acc1,0,0,0);
    acc2=__builtin_amdgcn_mfma_f32_16x16x32_bf16(ah,v2,acc2,0,0,0);
    acc2=__builtin_amdgcn_mfma_f32_16x16x32_bf16(al,v2,acc2,0,0,0);
    acc3=__builtin_amdgcn_mfma_f32_16x16x32_bf16(ah,v3,acc3,0,0,0);
    acc3=__builtin_amdgcn_mfma_f32_16x16x32_bf16(al,v3,acc3,0,0,0);
  }
  {
    int r0 = l4*4;
    #pragma unroll
    for (int q=0;q<4;q++){
      part[(r0+q)*PSX + w*64 +  0 + l15] = acc0[q];
      part[(r0+q)*PSX + w*64 + 16 + l15] = acc1[q];
      part[(r0+q)*PSX + w*64 + 32 + l15] = acc2[q];
      part[(r0+q)*PSX + w*64 + 48 + l15] = acc3[q];
    }
  }
  __syncthreads();
  float eb0=exb[j], eb1=exb[256+j], eb2=exb[512+j], eb3=exb[768+j];
  float c0s[4], h0s[4];
  #pragma unroll
  for (int q=0;q<4;q++){
    int r = 4*q + rp;
    int grow = row0 + r;
    bool g = grow < ROWS;
    float a0 = eb0 + part[r*PSX + j];
    float a1 = eb1 + part[r*PSX + 256 + j];
    float a2 = eb2 + part[r*PSX + 512 + j];
    float a3 = eb3 + part[r*PSX + 768 + j];
    float cp = g ? c0pg[grow*256 + j] : 0.f;
    float ii=sigf(a0), ff=sigf(a1), gg=tanh_fast(a2), oo=sigf(a3);
    float cn = ff*cp + ii*gg;
    float hn = oo*tanh_fast(cn);
    c0s[q]=cn; h0s[q]=hn;
    u16 hi = f2bf(hn);
    Ah[r*RSX + j] = hi; Al[r*RSX + j] = f2bf(hn - bf2f(hi));
    float hp = g ? h1pg[grow*256 + j] : 0.f;
    hi = f2bf(hp);
    Ah[r*RSX + 256 + j] = hi; Al[r*RSX + 256 + j] = f2bf(hp - bf2f(hi));
  }
  __syncthreads();
  acc0=(f32x4){0,0,0,0}; acc1=(f32x4){0,0,0,0}; acc2=(f32x4){0,0,0,0}; acc3=(f32x4){0,0,0,0};
  #pragma unroll 4
  for (int ks=0; ks<16; ks++){
    bfv8 ah = *(const bfv8*)&Ah[aoff + ks*32];
    bfv8 al = *(const bfv8*)&Al[aoff + ks*32];
    uint4 b0 = WBm[((w*4+0)*16 + ks)*64 + lane];
    uint4 b1 = WBm[((w*4+1)*16 + ks)*64 + lane];
    uint4 b2 = WBm[((w*4+2)*16 + ks)*64 + lane];
    uint4 b3 = WBm[((w*4+3)*16 + ks)*64 + lane];
    bfv8 v0=__builtin_bit_cast(bfv8,b0), v1=__builtin_bit_cast(bfv8,b1);
    bfv8 v2=__builtin_bit_cast(bfv8,b2), v3=__builtin_bit_cast(bfv8,b3);
    acc0=__builtin_amdgcn_mfma_f32_16x16x32_bf16(ah,v0,acc0,0,0,0);
    acc0=__builtin_amdgcn_mfma_f32_16x16x32_bf16(al,v0,acc0,0,0,0);
    acc1=__builtin_amdgcn_mfma_f32_16x16x32_bf16(ah,v1,acc1,0,0,0);
    acc1=__builtin_amdgcn_mfma_f32_16x16x32_bf16(al,v1,acc1,0,0,0);
    acc2=__builtin_amdgcn_mfma_f32_16x16x32_bf16(ah,v2,acc2,0,0,0);
    acc2=__builtin_amdgcn_mfma_f32_16x16x32_bf16(al,v2,acc2,0,0,0);
    acc3=__builtin_amdgcn_mfma_f32_16x16x32_bf16(ah,v3,acc3,0,0,0);
    acc3=__builtin_amdgcn_mfma_f32_16x16x32_bf16(al,v3,acc3,0,0,0);
  }
  {
    int r0 = l4*4;
    #pragma unroll
    for (int q=0;q<4;q++){
      part[(r0+q)*PSX + w*64 +  0 + l15] = acc0[q];
      part[(r0+q)*PSX + w*64 + 16 + l15] = acc1[q];
      part[(r0+q)*PSX + w*64 + 32 + l15] = acc2[q];
      part[(r0+q)*PSX + w*64 + 48 + l15] = acc3[q];
    }
  }
  __syncthreads();
  float eb4=exb[1024+j], eb5=exb[1280+j], eb6=exb[1536+j], eb7=exb[1792+j];
  #pragma unroll
  for (int q=0;q<4;q++){
    int r = 4*q + rp;
    int grow = row0 + r;
    bool g = grow < ROWS;
    float a0 = eb4 + part[r*PSX + j];
    float a1 = eb5 + part[r*PSX + 256 + j];
    float a2 = eb6 + part[r*PSX + 512 + j];
    float a3 = eb7 + part[r*PSX + 768 + j];
    float cp = g ? c1pg[grow*256 + j] : 0.f;
    float ii=sigf(a0), ff=sigf(a1), gg=tanh_fast(a2), oo=sigf(a3);
    float cn = ff*cp + ii*gg;
    float hn = oo*tanh_fast(cn);
    if (g){
      int o = grow*256 + j;
      c0o[o]=c0s[q]; h0o[o]=h0s[q]; c1o[o]=cn; h1o[o]=hn;
    }
    u16 hi;
    hi = f2bf(c0s[q]); Ah[r*RSX +       j] = hi; Al[r*RSX +       j] = f2bf(c0s[q]-bf2f(hi));
    hi = f2bf(h0s[q]); Ah[r*RSX + 256 + j] = hi; Al[r*RSX + 256 + j] = f2bf(h0s[q]-bf2f(hi));
    hi = f2bf(cn);     Ah[r*RSX + 512 + j] = hi; Al[r*RSX + 512 + j] = f2bf(cn-bf2f(hi));
    hi = f2bf(hn);     Ah[r*RSX + 768 + j] = hi; Al[r*RSX + 768 + j] = f2bf(hn-bf2f(hi));
  }
  __syncthreads();
  f32x4 accq = {0,0,0,0};
  #pragma unroll 4
  for (int ks=0; ks<32; ks++){
    bfv8 ah = *(const bfv8*)&Ah[aoff + ks*32];
    bfv8 al = *(const bfv8*)&Al[aoff + ks*32];
    uint4 b = WKm[(w*32 + ks)*64 + lane];
    bfv8 v = __builtin_bit_cast(bfv8, b);
    accq = __builtin_amdgcn_mfma_f32_16x16x32_bf16(ah, v, accq, 0,0,0);
    accq = __builtin_amdgcn_mfma_f32_16x16x32_bf16(al, v, accq, 0,0,0);
  }
  {
    int r0 = l4*4;
    #pragma unroll
    for (int q=0;q<4;q++)
      part[(r0+q)*260 + w*16 + l15] = accq[q];
  }
  __syncthreads();
  float bkv = bk[j];
  #pragma unroll
  for (int q=0;q<4;q++){
    int r = 4*q + rp;
    int grow = row0 + r;
    if (grow < ROWS) qb[grow*256 + j] = part[r*260 + j] + bkv;
  }
}

// ---------------- K6: out = h_exit @ wo + bo -----------------------------
__global__ __launch_bounds__(256) void k_out(
    const float* __restrict__ h1f, const int* __restrict__ exitIdx,
    const float* __restrict__ wo, const float* __restrict__ bo, float* __restrict__ out){
  __shared__ float hv[8][256];
  int tid = threadIdx.x;
  for (int i = tid; i < 2048; i += 256){
    int b = i >> 8, k = i & 255;
    hv[b][k] = h1f[(b*81 + exitIdx[b])*256 + k];
  }
  __syncthreads();
  int v = blockIdx.x*256 + tid;
  if (v >= 30000) return;
  float acc[8];
  #pragma unroll
  for (int b=0;b<8;b++) acc[b] = bo[v];
  for (int k=0;k<256;k++){
    float w = wo[k*30000 + v];
    #pragma unroll
    for (int b=0;b<8;b++) acc[b] = fmaf(hv[b][k], w, acc[b]);
  }
  #pragma unroll
  for (int b=0;b<8;b++) out[b*30000+v] = acc[b];
}

// ---------------- launch --------------------------------------------------
extern "C" void kernel_launch(void* const* d_in, const int* in_sizes, int n_in,
                              void* d_out, int out_size, void* d_ws, size_t ws_size,
                              hipStream_t stream){
  (void)in_sizes; (void)n_in; (void)out_size;
  const float* ne    = (const float*)d_in[0];
  const int*   exitI = (const int*)d_in[10];
  const float* stWx  = (const float*)d_in[12];
  const float* stb   = (const float*)d_in[14];
  const float* skWx  = (const float*)d_in[15];
  const float* skWh  = (const float*)d_in[16];
  const float* skb   = (const float*)d_in[17];
  const float* lnS   = (const float*)d_in[18];
  const float* lnB   = (const float*)d_in[19];
  const float* exWx  = (const float*)d_in[20];
  const float* exWh  = (const float*)d_in[21];
  const float* exb   = (const float*)d_in[22];
  const float* wk    = (const float*)d_in[23];
  const float* bk    = (const float*)d_in[24];
  const float* wsm   = (const float*)d_in[25];
  const float* bs    = (const float*)d_in[26];
  const float* w1    = (const float*)d_in[27];
  const float* wo    = (const float*)d_in[29];
  const float* bo    = (const float*)d_in[30];
  float* out = (float*)d_out;

  char* w = (char*)d_ws;
  size_t off = 0;
  auto alloc = [&](size_t bytes)->char*{
    char* p = w + off; off += (bytes + 255) & ~size_t(255); return p;
  };
  float4* X0   = (float4*)alloc((size_t)640*256*16);
  u32* W0m     = (u32*)alloc((size_t)131072*4);          // skip L0, K=256
  u32* W1m     = (u32*)alloc((size_t)262144*4);          // skip L1, K=512
  u32* WAm     = (u32*)alloc((size_t)262144*4);          // ex L0, K=512
  u32* WBm     = (u32*)alloc((size_t)262144*4);          // ex L1, K=512
  u32* WKm     = (u32*)alloc((size_t)131072*4);          // wk, K=1024 N=256
  u32* WSm     = (u32*)alloc((size_t)32768*4);           // ws, K=256 N=256
  float* skip  = (float*)alloc((size_t)8*81*81*256*4);   // fp32
  u16* keys    = (u16*)alloc((size_t)8*81*81*256*2);     // bf16
  float* tb    = (float*)alloc((size_t)ROWS*81*4);
  float* p0    = (float*)alloc(ROWS*4);
  float* p1    = (float*)alloc(ROWS*4);
  float* stA   = (float*)alloc((size_t)4*ROWS*256*4);
  float* stB   = (float*)alloc((size_t)4*ROWS*256*4);
  float* xinb  = (float*)alloc((size_t)ROWS*256*4);
  float* h0pb  = (float*)alloc((size_t)ROWS*256*4);
  float* h1pb  = (float*)alloc((size_t)ROWS*256*4);
  float* c0pb  = (float*)alloc((size_t)ROWS*256*4);
  float* c1pb  = (float*)alloc((size_t)ROWS*256*4);
  float* qb    = (float*)alloc((size_t)ROWS*256*4);
  float* exh0  = (float*)alloc((size_t)2*40*4*1024*4);   // double-buffered
  float* exh1  = (float*)alloc((size_t)40*4*1024*4);
  float* exst  = (float*)alloc((size_t)40*4*32*4);
  int*   flags = (int*)alloc((size_t)2048*4);
  if (off > ws_size) return;   // workspace too small — surfaces as absmax fail

  const size_t ST = (size_t)ROWS*256;
  float *A_c0=stA, *A_h0=stA+ST, *A_c1=stA+2*ST, *A_h1=stA+3*ST;
  float *B_c0=stB, *B_h0=stB+ST, *B_c1=stB+2*ST, *B_h1=stB+3*ST;

  hipMemsetAsync(skip, 0, (size_t)8*81*81*256*4, stream);
  hipMemsetAsync(stA, 0, (size_t)4*ROWS*256*4, stream);
  hipMemsetAsync(stB, 0, (size_t)4*ROWS*256*4, stream);
  hipMemsetAsync(flags, 0, (size_t)2048*4, stream);
  k_init_p<<<3,256,0,stream>>>(p0);

  pack_mfma<<<512, 256, 0, stream>>>(skWh, skWh, W0m, 256);                        // Wh0
  pack_mfma<<<1024,256, 0, stream>>>(skWx+256*1024, skWh+256*1024, W1m, 512);      // [Wx1;Wh1]
  pack_mfma<<<1024,256, 0, stream>>>(exWx, exWh, WAm, 512);                        // [exWx0;exWh0]
  pack_mfma<<<1024,256, 0, stream>>>(exWx+256*1024, exWh+256*1024, WBm, 512);      // [exWx1;exWh1]
  pack_w<<<512, 256, 0, stream>>>(wk, WKm, 1024, 16);
  pack_w<<<128, 256, 0, stream>>>(wsm, WSm, 256, 16);

  k_stmt_x0<<<320, 512, 0, stream>>>(ne, stWx, stb, skWx, skb, X0);
  k_skip_chains<<<160, 1024, 0, stream>>>(X0, (const uint4*)W0m, (const uint4*)W1m,
                                          skb, lnS, lnB, skip,
                                          exh0, exh1, exst, flags, flags+1024);
  k_keys<<<(KROWS+15)/16, 1024, 0, stream>>>(skip, (const uint4*)WSm, bs, keys);

  float* pc = p0; float* pn = p1;
  for (int s=0; s<8; s++){
    float *ic0,*ih0,*ic1,*ih1,*oc0,*oh0,*oc1,*oh1;
    if ((s & 1) == 0){ ic0=A_c0; ih0=A_h0; ic1=A_c1; ih1=A_h1; oc0=B_c0; oh0=B_h0; oc1=B_c1; oh1=B_h1; }
    else             { ic0=B_c0; ih0=B_h0; ic1=B_c1; ih1=B_h1; oc0=A_c0; oh0=A_h0; oc1=A_c1; oh1=A_h1; }
    int mode = (s==0) ? 0 : ((s==7) ? 2 : 1);
    k_attn<<<648, 256, 0, stream>>>(qb, keys, w1, pc, tb, mode);
    k_gather<<<648, 256, 0, stream>>>(tb, skip, ic0, ih0, ic1, ih1,
                                      xinb, h0pb, h1pb, c0pb, c1pb, pn);
    k_exlstm<<<41, 1024, 0, stream>>>(xinb, h0pb, h1pb, c0pb, c1pb,
                                      (const uint4*)WAm, (const uint4*)WBm,
                                      (const uint4*)WKm, exb, bk,
                                      oc0, oh0, oc1, oh1, qb);
    float* tmp = pc; pc = pn; pn = tmp;
  }
  // final states are in buffer A (step 7 writes A)
  k_out<<<(30000+255)/256, 256, 0, stream>>>(A_h1, exitI, wo, bo, out);
}

// Round 8
// 2029.499 us; speedup vs baseline: 3.3508x; 3.3508x over previous
//
#include <hip/hip_runtime.h>

typedef unsigned int  u32;
typedef unsigned short u16;
typedef float v2f __attribute__((ext_vector_type(2)));
typedef __attribute__((ext_vector_type(8))) short bfv8;   // 8 bf16 = 4 VGPR
typedef __attribute__((ext_vector_type(4))) float f32x4;

// B=8, NS=80, NN=81, H=256, L=2, STEPS=8, VOCAB=30000
#define ROWS 648          // B*NN
#define KROWS 52488       // 8*81*81 skip rows

__device__ __forceinline__ float sigf(float x){ return 1.0f/(1.0f+__expf(-x)); }
__device__ __forceinline__ float tanh_fast(float x){
  float e = __expf(-2.0f*fabsf(x));
  float r = (1.0f-e)/(1.0f+e);
  return copysignf(r,x);
}
__device__ __forceinline__ u16 f2bf(float f){        // RTNE f32->bf16
  u32 u = __float_as_uint(f);
  u += 0x7FFFu + ((u>>16)&1u);
  return (u16)(u>>16);
}
__device__ __forceinline__ u32 packbf2(float lo, float hi){
  return (u32)f2bf(lo) | ((u32)f2bf(hi)<<16);
}
__device__ __forceinline__ float bf2f(u16 v){ return __uint_as_float(((u32)v)<<16); }

// ---------------- weight packing ----------------------------------------
// MFMA B-fragment pack, concat two [256 x 1024] sources along K (N=1024).
// frag (tile t, kstep ks): lane l holds B[k = ks*32+(l>>4)*8+e][col = t*16+(l&15)]
__global__ void pack_mfma(const float* __restrict__ A, const float* __restrict__ Bm,
                          u32* __restrict__ dst, int K){
  int id = blockIdx.x*256 + threadIdx.x;
  int KS = K >> 5;
  int tot = 64*KS*64*4;
  if (id >= tot) return;
  int e2 = id & 3;
  int l  = (id >> 2) & 63;
  int rest = id >> 8;
  int ks = rest % KS;
  int t  = rest / KS;
  int k  = ks*32 + (l>>4)*8 + e2*2;
  int col = t*16 + (l&15);
  float v0 = (k   < 256) ? A[k*1024 + col]       : Bm[(k-256)*1024 + col];
  float v1 = (k+1 < 256) ? A[(k+1)*1024 + col]   : Bm[(k+1-256)*1024 + col];
  dst[id] = packbf2(v0, v1);
}

// Generic MFMA B-frag pack from one [K x (NT*16)] row-major matrix.
__global__ void pack_w(const float* __restrict__ src, u32* __restrict__ dst,
                       int K, int NT){
  int id = blockIdx.x*256 + threadIdx.x;
  int KS = K >> 5;
  int tot = NT*KS*64*4;
  if (id >= tot) return;
  int e2 = id & 3;
  int l  = (id >> 2) & 63;
  int rest = id >> 8;
  int ks = rest % KS;
  int t  = rest / KS;
  int k  = ks*32 + (l>>4)*8 + e2*2;
  int col = t*16 + (l&15);
  int ld = NT*16;
  dst[id] = packbf2(src[k*ld + col], src[(k+1)*ld + col]);
}

__global__ void k_init_p(float* __restrict__ p0){
  int i = blockIdx.x*256 + threadIdx.x;
  if (i < ROWS) p0[i] = ((i % 81)==0) ? 1.0f : 0.0f;
}

// ---------------- K1: statement embedder + X0 precompute ----------------
__global__ __launch_bounds__(512) void k_stmt_x0(
    const float* __restrict__ ne, const float* __restrict__ stWx, const float* __restrict__ stb,
    const float* __restrict__ skWx, const float* __restrict__ skb, float4* __restrict__ X0){
  __shared__ float xv[2][256];
  __shared__ float hv[2][256];
  int r = threadIdx.x >> 8, j = threadIdx.x & 255;
  int bn = blockIdx.x*2 + r;                    // 0..639
  xv[r][j] = ne[bn*256 + j];
  __syncthreads();
  float a0=stb[j], a2=stb[512+j], a3=stb[768+j];
  for (int k=0;k<256;k++){
    float x = xv[r][k];
    const float* w = stWx + k*1024;
    a0 = fmaf(x, w[j], a0); a2 = fmaf(x, w[512+j], a2); a3 = fmaf(x, w[768+j], a3);
  }
  float c = sigf(a0)*tanh_fast(a2);
  float h = sigf(a3)*tanh_fast(c);
  hv[r][j] = h;
  __syncthreads();
  a0=stb[1024+j]; a2=stb[1536+j]; a3=stb[1792+j];
  const float* W1 = stWx + 256*1024;
  for (int k=0;k<256;k++){
    float x = hv[r][k];
    const float* w = W1 + k*1024;
    a0 = fmaf(x, w[j], a0); a2 = fmaf(x, w[512+j], a2); a3 = fmaf(x, w[768+j], a3);
  }
  c = sigf(a0)*tanh_fast(a2);
  h = sigf(a3)*tanh_fast(c);
  __syncthreads();
  xv[r][j] = h;           // stmt row
  __syncthreads();
  float b0=skb[j], b1g=skb[256+j], b2=skb[512+j], b3=skb[768+j];
  for (int k=0;k<256;k++){
    float x = xv[r][k];
    const float* w = skWx + k*1024;
    b0 = fmaf(x, w[j], b0);     b1g = fmaf(x, w[256+j], b1g);
    b2 = fmaf(x, w[512+j], b2); b3 = fmaf(x, w[768+j], b3);
  }
  X0[bn*256 + j] = make_float4(b0,b1g,b2,b3);
}

// ---------------- K3: skip-encoder chains (MFMA) -------------------------
// M-tile = 16 rows, rows 8-15 ZERO PADDING; D-store via lanes<32 (rows 0-7).
// NOTE (R6/R7 lessons): W1 register-residency is impossible at 16 waves/block
// (VGPR cap 128/thread -> silent scratch spill, 2.2x regression); 4-block
// j-split cross-CU sync costs ~60us/step (4.7x regression). Per-chain state
// must stay on ONE CU; ~16us/step (10us L2 weight stream) is this
// decomposition's floor.
#define RS0 264   // A-buf row stride (u16), layer0 K=256 (+8 pad)
#define RS1 520   // layer1 K=512 (+8 pad)
#define PS  1028  // part row stride (f32)
__global__ __launch_bounds__(1024) void k_skip_chains(
    const float4* __restrict__ X0,
    const uint4* __restrict__ W0m, const uint4* __restrict__ W1m,
    const float* __restrict__ skb, const float* __restrict__ lnS, const float* __restrict__ lnB,
    float* __restrict__ skip){
  int s  = blockIdx.x;
  int tid = threadIdx.x;
  int w = tid >> 6, lane = tid & 63;
  int l15 = lane & 15, l4 = lane >> 4;
  int rp = tid >> 8, j = tid & 255;     // cell role: rows rp and rp+4
  __shared__ float part[8*PS];          // 32.9KB  D[row][col]
  __shared__ u16 A0h[16*RS0], A0l[16*RS0];  // layer0 A: h0_ln hi/lo
  __shared__ u16 A1h[16*RS1], A1l[16*RS1];  // layer1 A: [h0_raw | h1_ln] hi/lo
  __shared__ float red[4][16];
  for (int i=tid; i<16*RS0; i+=1024){ A0h[i]=0; A0l[i]=0; }
  for (int i=tid; i<16*RS1; i+=1024){ A1h[i]=0; A1l[i]=0; }
  float c0a=0.f, c1a=0.f, c0b=0.f, c1b=0.f;   // states rows rp / rp+4
  float s1b0=skb[1024+j], s1b1=skb[1280+j], s1b2=skb[1536+j], s1b3=skb[1792+j];
  float lS0=lnS[j], lS1=lnS[256+j], lS2=lnS[512+j], lS3=lnS[768+j];
  float lB0=lnB[j], lB1=lnB[256+j], lB2=lnB[512+j], lB3=lnB[768+j];
  const int aoff0 = l15*RS0 + l4*8;
  const int aoff1 = l15*RS1 + l4*8;
  __syncthreads();
  for (int idx=s; idx<80; idx++){
    float4 gxa = X0[(rp*80+idx)*256 + j];       // x-part gates, row rp
    float4 gxb = X0[((rp+4)*80+idx)*256 + j];   // row rp+4
    // ---- layer0 matvec: A0(h0_ln) x W0, K=256 (8 ksteps, streamed)
    f32x4 acc0={0,0,0,0}, acc1={0,0,0,0}, acc2={0,0,0,0}, acc3={0,0,0,0};
    #pragma unroll 4
    for (int ks=0; ks<8; ks++){
      bfv8 ah = *(const bfv8*)&A0h[aoff0 + ks*32];
      bfv8 al = *(const bfv8*)&A0l[aoff0 + ks*32];
      uint4 b0 = W0m[((w*4+0)*8 + ks)*64 + lane];
      uint4 b1 = W0m[((w*4+1)*8 + ks)*64 + lane];
      uint4 b2 = W0m[((w*4+2)*8 + ks)*64 + lane];
      uint4 b3 = W0m[((w*4+3)*8 + ks)*64 + lane];
      bfv8 v0=__builtin_bit_cast(bfv8,b0), v1=__builtin_bit_cast(bfv8,b1);
      bfv8 v2=__builtin_bit_cast(bfv8,b2), v3=__builtin_bit_cast(bfv8,b3);
      acc0=__builtin_amdgcn_mfma_f32_16x16x32_bf16(ah,v0,acc0,0,0,0);
      acc0=__builtin_amdgcn_mfma_f32_16x16x32_bf16(al,v0,acc0,0,0,0);
      acc1=__builtin_amdgcn_mfma_f32_16x16x32_bf16(ah,v1,acc1,0,0,0);
      acc1=__builtin_amdgcn_mfma_f32_16x16x32_bf16(al,v1,acc1,0,0,0);
      acc2=__builtin_amdgcn_mfma_f32_16x16x32_bf16(ah,v2,acc2,0,0,0);
      acc2=__builtin_amdgcn_mfma_f32_16x16x32_bf16(al,v2,acc2,0,0,0);
      acc3=__builtin_amdgcn_mfma_f32_16x16x32_bf16(ah,v3,acc3,0,0,0);
      acc3=__builtin_amdgcn_mfma_f32_16x16x32_bf16(al,v3,acc3,0,0,0);
    }
    if (lane < 32){
      int r0 = l4*4;
      #pragma unroll
      for (int q=0;q<4;q++){
        part[(r0+q)*PS + w*64 +  0 + l15] = acc0[q];
        part[(r0+q)*PS + w*64 + 16 + l15] = acc1[q];
        part[(r0+q)*PS + w*64 + 32 + l15] = acc2[q];
        part[(r0+q)*PS + w*64 + 48 + l15] = acc3[q];
      }
    }
    __syncthreads();                       // B1
    // ---- layer0 cell, rows rp and rp+4
    float h0na, h0nb;
    {
      float a0=gxa.x+part[rp*PS+j],     a1=gxa.y+part[rp*PS+256+j];
      float a2=gxa.z+part[rp*PS+512+j], a3=gxa.w+part[rp*PS+768+j];
      float ii=sigf(a0), ff=sigf(a1), gg=tanh_fast(a2), oo=sigf(a3);
      c0a = ff*c0a + ii*gg;
      h0na = oo*tanh_fast(c0a);
      u16 hi = f2bf(h0na);
      A1h[rp*RS1 + j] = hi;
      A1l[rp*RS1 + j] = f2bf(h0na - bf2f(hi));
    }
    {
      int rb = rp+4;
      float a0=gxb.x+part[rb*PS+j],     a1=gxb.y+part[rb*PS+256+j];
      float a2=gxb.z+part[rb*PS+512+j], a3=gxb.w+part[rb*PS+768+j];
      float ii=sigf(a0), ff=sigf(a1), gg=tanh_fast(a2), oo=sigf(a3);
      c0b = ff*c0b + ii*gg;
      h0nb = oo*tanh_fast(c0b);
      u16 hi = f2bf(h0nb);
      A1h[rb*RS1 + j] = hi;
      A1l[rb*RS1 + j] = f2bf(h0nb - bf2f(hi));
    }
    __syncthreads();                       // B2
    // ---- layer1 matvec: A1([h0_raw|h1_ln]) x W1, K=512 (16 ksteps)
    acc0=(f32x4){0,0,0,0}; acc1=(f32x4){0,0,0,0}; acc2=(f32x4){0,0,0,0}; acc3=(f32x4){0,0,0,0};
    #pragma unroll 4
    for (int ks=0; ks<16; ks++){
      bfv8 ah = *(const bfv8*)&A1h[aoff1 + ks*32];
      bfv8 al = *(const bfv8*)&A1l[aoff1 + ks*32];
      uint4 b0 = W1m[((w*4+0)*16 + ks)*64 + lane];
      uint4 b1 = W1m[((w*4+1)*16 + ks)*64 + lane];
      uint4 b2 = W1m[((w*4+2)*16 + ks)*64 + lane];
      uint4 b3 = W1m[((w*4+3)*16 + ks)*64 + lane];
      bfv8 v0=__builtin_bit_cast(bfv8,b0), v1=__builtin_bit_cast(bfv8,b1);
      bfv8 v2=__builtin_bit_cast(bfv8,b2), v3=__builtin_bit_cast(bfv8,b3);
      acc0=__builtin_amdgcn_mfma_f32_16x16x32_bf16(ah,v0,acc0,0,0,0);
      acc0=__builtin_amdgcn_mfma_f32_16x16x32_bf16(al,v0,acc0,0,0,0);
      acc1=__builtin_amdgcn_mfma_f32_16x16x32_bf16(ah,v1,acc1,0,0,0);
      acc1=__builtin_amdgcn_mfma_f32_16x16x32_bf16(al,v1,acc1,0,0,0);
      acc2=__builtin_amdgcn_mfma_f32_16x16x32_bf16(ah,v2,acc2,0,0,0);
      acc2=__builtin_amdgcn_mfma_f32_16x16x32_bf16(al,v2,acc2,0,0,0);
      acc3=__builtin_amdgcn_mfma_f32_16x16x32_bf16(ah,v3,acc3,0,0,0);
      acc3=__builtin_amdgcn_mfma_f32_16x16x32_bf16(al,v3,acc3,0,0,0);
    }
    if (lane < 32){
      int r0 = l4*4;
      #pragma unroll
      for (int q=0;q<4;q++){
        part[(r0+q)*PS + w*64 +  0 + l15] = acc0[q];
        part[(r0+q)*PS + w*64 + 16 + l15] = acc1[q];
        part[(r0+q)*PS + w*64 + 32 + l15] = acc2[q];
        part[(r0+q)*PS + w*64 + 48 + l15] = acc3[q];
      }
    }
    __syncthreads();                       // B3
    // ---- layer1 cell + LN, rows rp and rp+4
    float h1na, h1nb;
    {
      float a0=s1b0+part[rp*PS+j],     a1=s1b1+part[rp*PS+256+j];
      float a2=s1b2+part[rp*PS+512+j], a3=s1b3+part[rp*PS+768+j];
      float ii=sigf(a0), ff=sigf(a1), gg=tanh_fast(a2), oo=sigf(a3);
      c1a = ff*c1a + ii*gg;
      h1na = oo*tanh_fast(c1a);
      skip[((rp*81 + s)*81 + (idx+1))*256 + j] = h1na;
    }
    {
      int rb = rp+4;
      float a0=s1b0+part[rb*PS+j],     a1=s1b1+part[rb*PS+256+j];
      float a2=s1b2+part[rb*PS+512+j], a3=s1b3+part[rb*PS+768+j];
      float ii=sigf(a0), ff=sigf(a1), gg=tanh_fast(a2), oo=sigf(a3);
      c1b = ff*c1b + ii*gg;
      h1nb = oo*tanh_fast(c1b);
      skip[((rb*81 + s)*81 + (idx+1))*256 + j] = h1nb;
    }
    // ---- LayerNorm over concat(c0,h0n,c1,h1n) per row (1024 elems)
    float sm0 = c0a + h0na + c1a + h1na;
    float sq0 = c0a*c0a + h0na*h0na + c1a*c1a + h1na*h1na;
    float sm1 = c0b + h0nb + c1b + h1nb;
    float sq1 = c0b*c0b + h0nb*h0nb + c1b*c1b + h1nb*h1nb;
    #pragma unroll
    for (int off=32; off; off>>=1){
      sm0 += __shfl_xor(sm0, off); sq0 += __shfl_xor(sq0, off);
      sm1 += __shfl_xor(sm1, off); sq1 += __shfl_xor(sq1, off);
    }
    int wq = j >> 6;
    if ((j & 63) == 0){
      red[rp][wq*4+0]=sm0; red[rp][wq*4+1]=sq0;
      red[rp][wq*4+2]=sm1; red[rp][wq*4+3]=sq1;
    }
    __syncthreads();                       // B4
    sm0 = red[rp][0]+red[rp][4]+red[rp][8]+red[rp][12];
    sq0 = red[rp][1]+red[rp][5]+red[rp][9]+red[rp][13];
    sm1 = red[rp][2]+red[rp][6]+red[rp][10]+red[rp][14];
    sq1 = red[rp][3]+red[rp][7]+red[rp][11]+red[rp][15];
    {
      float mu = sm0 * (1.0f/1024.0f);
      float var = sq0 * (1.0f/1024.0f) - mu*mu;
      float rstd = rsqrtf(var + 1e-6f);
      c0a = (c0a - mu)*rstd*lS0 + lB0;
      float h0ln = (h0na - mu)*rstd*lS1 + lB1;
      c1a = (c1a - mu)*rstd*lS2 + lB2;
      float h1ln = (h1na - mu)*rstd*lS3 + lB3;
      u16 hi = f2bf(h0ln);
      A0h[rp*RS0 + j] = hi; A0l[rp*RS0 + j] = f2bf(h0ln - bf2f(hi));
      hi = f2bf(h1ln);
      A1h[rp*RS1 + 256 + j] = hi; A1l[rp*RS1 + 256 + j] = f2bf(h1ln - bf2f(hi));
    }
    {
      int rb = rp+4;
      float mu = sm1 * (1.0f/1024.0f);
      float var = sq1 * (1.0f/1024.0f) - mu*mu;
      float rstd = rsqrtf(var + 1e-6f);
      c0b = (c0b - mu)*rstd*lS0 + lB0;
      float h0ln = (h0nb - mu)*rstd*lS1 + lB1;
      c1b = (c1b - mu)*rstd*lS2 + lB2;
      float h1ln = (h1nb - mu)*rstd*lS3 + lB3;
      u16 hi = f2bf(h0ln);
      A0h[rb*RS0 + j] = hi; A0l[rb*RS0 + j] = f2bf(h0ln - bf2f(hi));
      hi = f2bf(h1ln);
      A1h[rb*RS1 + 256 + j] = hi; A1l[rb*RS1 + 256 + j] = f2bf(h1ln - bf2f(hi));
    }
    __syncthreads();                       // B5
  }
}

// ---------------- K4: keys = skip @ ws + bs  (MFMA, bf16 out) ------------
// grid 3281 x 1024 thr (16 waves). M-tile 16 skip rows; N=256 (wave w: tile w).
__global__ __launch_bounds__(1024) void k_keys(const float* __restrict__ skip,
    const uint4* __restrict__ WSm, const float* __restrict__ bs, u16* __restrict__ keys){
  int rows0 = blockIdx.x*16;
  int tid = threadIdx.x;
  int w = tid >> 6, lane = tid & 63;
  int l15 = lane & 15, l4 = lane >> 4;
  __shared__ u16 Ah[16*RS0], Al[16*RS0];
  __shared__ u16 kbuf[16*256];
  { // stage row w (fp32 -> hi/lo bf16)
    int grow = rows0 + w;
    float4 v = {0,0,0,0};
    if (grow < KROWS) v = ((const float4*)skip)[grow*64 + lane];
    ushort4 hi4, lo4;
    hi4.x=f2bf(v.x); lo4.x=f2bf(v.x-bf2f(hi4.x));
    hi4.y=f2bf(v.y); lo4.y=f2bf(v.y-bf2f(hi4.y));
    hi4.z=f2bf(v.z); lo4.z=f2bf(v.z-bf2f(hi4.z));
    hi4.w=f2bf(v.w); lo4.w=f2bf(v.w-bf2f(hi4.w));
    *(ushort4*)&Ah[w*RS0 + lane*4] = hi4;
    *(ushort4*)&Al[w*RS0 + lane*4] = lo4;
  }
  __syncthreads();
  const int aoff = l15*RS0 + l4*8;
  f32x4 acc = {0,0,0,0};
  #pragma unroll
  for (int ks=0; ks<8; ks++){
    bfv8 ah = *(const bfv8*)&Ah[aoff + ks*32];
    bfv8 al = *(const bfv8*)&Al[aoff + ks*32];
    uint4 b = WSm[(w*8 + ks)*64 + lane];
    bfv8 v = __builtin_bit_cast(bfv8, b);
    acc = __builtin_amdgcn_mfma_f32_16x16x32_bf16(ah, v, acc, 0,0,0);
    acc = __builtin_amdgcn_mfma_f32_16x16x32_bf16(al, v, acc, 0,0,0);
  }
  float bsv = bs[w*16 + l15];
  #pragma unroll
  for (int q=0;q<4;q++)
    kbuf[(l4*4+q)*256 + w*16 + l15] = f2bf(acc[q] + bsv);
  __syncthreads();
  int nval = KROWS - rows0; if (nval > 16) nval = 16;
  int words = nval*128;                 // u32 words (256 u16 per row)
  u32* kout = (u32*)keys + (size_t)rows0*128;
  const u32* kin = (const u32*)kbuf;
  for (int i=tid; i<words; i+=1024) kout[i] = kin[i];
}

// ---------------- Kb: logits -> softmax -> t (q precomputed) -------------
// mode 0: t[n,1]=pv. mode 2: t[n,80]=pv. mode 1: full masked softmax.
__global__ __launch_bounds__(256) void k_attn(
    const float* __restrict__ qb, const u16* __restrict__ keys,
    const float* __restrict__ w1, const float* __restrict__ pcur,
    float* __restrict__ t, int mode){
  int bn = blockIdx.x; int n = bn % 81;
  int tid = threadIdx.x;
  float pv = pcur[bn];
  if (pv == 0.0f){
    if (tid < 81) t[bn*81 + tid] = 0.0f;
    return;
  }
  if (mode == 0){ if (tid < 81) t[bn*81 + tid] = (tid==1)  ? pv : 0.0f; return; }
  if (mode == 2){ if (tid < 81) t[bn*81 + tid] = (tid==80) ? pv : 0.0f; return; }
  __shared__ float qv[256];
  __shared__ float lg[81];
  qv[tid] = qb[bn*256 + tid];
  if (tid < 81) lg[tid] = -3e38f;
  __syncthreads();
  int lane = tid & 63, wv = tid >> 6;
  float w1v0 = w1[lane], w1v1 = w1[64+lane], w1v2 = w1[128+lane], w1v3 = w1[192+lane];
  for (int m = wv; m < 81; m += 4){
    if (!(m>n || m==80)) continue;
    const u16* kr = keys + (bn*81+m)*256;
    float acc;
    acc  = tanh_fast(qv[lane]     + bf2f(kr[lane]))     * w1v0;
    acc += tanh_fast(qv[64+lane]  + bf2f(kr[64+lane]))  * w1v1;
    acc += tanh_fast(qv[128+lane] + bf2f(kr[128+lane])) * w1v2;
    acc += tanh_fast(qv[192+lane] + bf2f(kr[192+lane])) * w1v3;
    #pragma unroll
    for (int off=32; off; off>>=1) acc += __shfl_xor(acc, off);
    if (lane==0) lg[m] = acc;      // b1 omitted: softmax-invariant
  }
  __syncthreads();
  if (tid < 64){
    float v1 = lg[tid];
    float v2 = (tid<17) ? lg[64+tid] : -3e38f;
    float mx = fmaxf(v1, v2);
    #pragma unroll
    for (int off=32; off; off>>=1) mx = fmaxf(mx, __shfl_xor(mx, off));
    float e1 = __expf(v1-mx);
    float e2 = (tid<17) ? __expf(v2-mx) : 0.0f;
    float ssum = e1+e2;
    #pragma unroll
    for (int off=32; off; off>>=1) ssum += __shfl_xor(ssum, off);
    float sc = pv / ssum;
    t[bn*81 + tid] = e1*sc;
    if (tid<17) t[bn*81 + 64+tid] = e2*sc;
  }
}

// ---------------- Kg: gather einsums (x_in + state props + new_p) --------
__global__ __launch_bounds__(256) void k_gather(
    const float* __restrict__ t, const float* __restrict__ skip,
    const float* __restrict__ c0i, const float* __restrict__ h0i,
    const float* __restrict__ c1i, const float* __restrict__ h1i,
    float* __restrict__ xin, float* __restrict__ h0p,
    float* __restrict__ h1p, float* __restrict__ c0p,
    float* __restrict__ c1p, float* __restrict__ pnext){
  int row = blockIdx.x;           // b*81+m
  int b = row / 81, m = row - b*81;
  int tid = threadIdx.x;
  __shared__ float tcol[81];
  if (tid < 81) tcol[tid] = t[(b*81+tid)*81 + m];
  __syncthreads();
  int nlim = (m==80) ? 81 : m;    // t[n,m]==0 for n>=m (unless m==80)
  float ts = 0.f;
  for (int n=0;n<nlim;n++) ts += tcol[n];
  if (tid==0) pnext[row] = ts;
  int o = row*256 + tid;
  if (ts == 0.0f){
    xin[o]=0.f; h0p[o]=0.f; h1p[o]=0.f; c0p[o]=0.f; c1p[o]=0.f;
    return;
  }
  float xa=0.f, c0a=0.f, h0a=0.f, c1a=0.f, h1a=0.f;
  for (int n=0;n<nlim;n++){
    float tv = tcol[n];
    int st = (b*81+n)*256 + tid;
    xa  = fmaf(tv, skip[((b*81+n)*81 + m)*256 + tid], xa);
    c0a = fmaf(tv, c0i[st], c0a);
    h0a = fmaf(tv, h0i[st], h0a);
    c1a = fmaf(tv, c1i[st], c1a);
    h1a = fmaf(tv, h1i[st], h1a);
  }
  float inv = 1.0f/(ts + 1e-7f);
  xin[o]=xa*inv; h0p[o]=h0a*inv; h1p[o]=h1a*inv; c0p[o]=c0a*inv; c1p[o]=c1a*inv;
}

// ---------------- Kx: ex-LSTM step + fused q via MFMA --------------------
// grid 41 x 1024 thr. M-tile 16 REAL rows (D-store uses all 64 lanes).
// After states: q = [c0|h0|c1|h1] @ wk + bk (K=1024, N=256, tile = wave).
#define RSX 1032
#define PSX 1028
__global__ __launch_bounds__(1024) void k_exlstm(
    const float* __restrict__ xin, const float* __restrict__ h0pg,
    const float* __restrict__ h1pg, const float* __restrict__ c0pg,
    const float* __restrict__ c1pg,
    const uint4* __restrict__ WAm, const uint4* __restrict__ WBm,
    const uint4* __restrict__ WKm,
    const float* __restrict__ exb, const float* __restrict__ bk,
    float* __restrict__ c0o, float* __restrict__ h0o,
    float* __restrict__ c1o, float* __restrict__ h1o,
    float* __restrict__ qb){
  int row0 = blockIdx.x*16;
  int tid = threadIdx.x;
  int w = tid >> 6, lane = tid & 63;
  int l15 = lane & 15, l4 = lane >> 4;
  int rp = tid >> 8, j = tid & 255;
  __shared__ float part[16*PSX];        // 65.8KB
  __shared__ u16 Ah[16*RSX], Al[16*RSX];// 33KB each
  // ---- stage layer0 A: cols 0-255 x_in, 256-511 h0p (hi/lo planes)
  {
    int grow = row0 + w;
    float4 vx = {0,0,0,0}, vh = {0,0,0,0};
    if (grow < ROWS){
      vx = ((const float4*)xin)[grow*64 + lane];
      vh = ((const float4*)h0pg)[grow*64 + lane];
    }
    ushort4 hi4, lo4;
    hi4.x=f2bf(vx.x); lo4.x=f2bf(vx.x-bf2f(hi4.x));
    hi4.y=f2bf(vx.y); lo4.y=f2bf(vx.y-bf2f(hi4.y));
    hi4.z=f2bf(vx.z); lo4.z=f2bf(vx.z-bf2f(hi4.z));
    hi4.w=f2bf(vx.w); lo4.w=f2bf(vx.w-bf2f(hi4.w));
    *(ushort4*)&Ah[w*RSX + lane*4] = hi4;
    *(ushort4*)&Al[w*RSX + lane*4] = lo4;
    hi4.x=f2bf(vh.x); lo4.x=f2bf(vh.x-bf2f(hi4.x));
    hi4.y=f2bf(vh.y); lo4.y=f2bf(vh.y-bf2f(hi4.y));
    hi4.z=f2bf(vh.z); lo4.z=f2bf(vh.z-bf2f(hi4.z));
    hi4.w=f2bf(vh.w); lo4.w=f2bf(vh.w-bf2f(hi4.w));
    *(ushort4*)&Ah[w*RSX + 256 + lane*4] = hi4;
    *(ushort4*)&Al[w*RSX + 256 + lane*4] = lo4;
  }
  __syncthreads();
  const int aoff = l15*RSX + l4*8;
  // ---- layer0 matvec (16 ksteps, 2 planes, 4 tiles/wave)
  f32x4 acc0={0,0,0,0}, acc1={0,0,0,0}, acc2={0,0,0,0}, acc3={0,0,0,0};
  #pragma unroll 4
  for (int ks=0; ks<16; ks++){
    bfv8 ah = *(const bfv8*)&Ah[aoff + ks*32];
    bfv8 al = *(const bfv8*)&Al[aoff + ks*32];
    uint4 b0 = WAm[((w*4+0)*16 + ks)*64 + lane];
    uint4 b1 = WAm[((w*4+1)*16 + ks)*64 + lane];
    uint4 b2 = WAm[((w*4+2)*16 + ks)*64 + lane];
    uint4 b3 = WAm[((w*4+3)*16 + ks)*64 + lane];
    bfv8 v0=__builtin_bit_cast(bfv8,b0), v1=__builtin_bit_cast(bfv8,b1);
    bfv8 v2=__builtin_bit_cast(bfv8,b2), v3=__builtin_bit_cast(bfv8,b3);
    acc0=__builtin_amdgcn_mfma_f32_16x16x32_bf16(ah,v0,acc0,0,0,0);
    acc0=__builtin_amdgcn_mfma_f32_16x16x32_bf16(al,v0,acc0,0,0,0);
    acc1=__builtin_amdgcn_mfma_f32_16x16x32_bf16(ah,v1,acc1,0,0,0);
    acc1=__builtin_amdgcn_mfma_f32_16x16x32_bf16(al,v1,acc1,0,0,0);
    acc2=__builtin_amdgcn_mfma_f32_16x16x32_bf16(ah,v2,acc2,0,0,0);
    acc2=__builtin_amdgcn_mfma_f32_16x16x32_bf16(al,v2,acc2,0,0,0);
    acc3=__builtin_amdgcn_mfma_f32_16x16x32_bf16(ah,v3,acc3,0,0,0);
    acc3=__builtin_amdgcn_mfma_f32_16x16x32_bf16(al,v3,acc3,0,0,0);
  }
  {
    int r0 = l4*4;                       // ALL 64 lanes: rows 0-15
    #pragma unroll
    for (int q=0;q<4;q++){
      part[(r0+q)*PSX + w*64 +  0 + l15] = acc0[q];
      part[(r0+q)*PSX + w*64 + 16 + l15] = acc1[q];
      part[(r0+q)*PSX + w*64 + 32 + l15] = acc2[q];
      part[(r0+q)*PSX + w*64 + 48 + l15] = acc3[q];
    }
  }
  __syncthreads();
  // ---- layer0 cell: rows 4q+rp; write h0n + h1p into A for layer1
  float eb0=exb[j], eb1=exb[256+j], eb2=exb[512+j], eb3=exb[768+j];
  float c0s[4], h0s[4];
  #pragma unroll
  for (int q=0;q<4;q++){
    int r = 4*q + rp;
    int grow = row0 + r;
    bool g = grow < ROWS;
    float a0 = eb0 + part[r*PSX + j];
    float a1 = eb1 + part[r*PSX + 256 + j];
    float a2 = eb2 + part[r*PSX + 512 + j];
    float a3 = eb3 + part[r*PSX + 768 + j];
    float cp = g ? c0pg[grow*256 + j] : 0.f;
    float ii=sigf(a0), ff=sigf(a1), gg=tanh_fast(a2), oo=sigf(a3);
    float cn = ff*cp + ii*gg;
    float hn = oo*tanh_fast(cn);
    c0s[q]=cn; h0s[q]=hn;
    u16 hi = f2bf(hn);
    Ah[r*RSX + j] = hi; Al[r*RSX + j] = f2bf(hn - bf2f(hi));
    float hp = g ? h1pg[grow*256 + j] : 0.f;
    hi = f2bf(hp);
    Ah[r*RSX + 256 + j] = hi; Al[r*RSX + 256 + j] = f2bf(hp - bf2f(hi));
  }
  __syncthreads();
  // ---- layer1 matvec
  acc0=(f32x4){0,0,0,0}; acc1=(f32x4){0,0,0,0}; acc2=(f32x4){0,0,0,0}; acc3=(f32x4){0,0,0,0};
  #pragma unroll 4
  for (int ks=0; ks<16; ks++){
    bfv8 ah = *(const bfv8*)&Ah[aoff + ks*32];
    bfv8 al = *(const bfv8*)&Al[aoff + ks*32];
    uint4 b0 = WBm[((w*4+0)*16 + ks)*64 + lane];
    uint4 b1 = WBm[((w*4+1)*16 + ks)*64 + lane];
    uint4 b2 = WBm[((w*4+2)*16 + ks)*64 + lane];
    uint4 b3 = WBm[((w*4+3)*16 + ks)*64 + lane];
    bfv8 v0=__builtin_bit_cast(bfv8,b0), v1=__builtin_bit_cast(bfv8,b1);
    bfv8 v2=__builtin_bit_cast(bfv8,b2), v3=__builtin_bit_cast(bfv8,b3);
    acc0=__builtin_amdgcn_mfma_f32_16x16x32_bf16(ah,v0,acc0,0,0,0);
    acc0=__builtin_amdgcn_mfma_f32_16x16x32_bf16(al,v0,acc0,0,0,0);
    acc1=__builtin_amdgcn_mfma_f32_16x16x32_bf16(ah,v1,acc1,0,0,0);
    acc1=__builtin_amdgcn_mfma_f32_16x16x32_bf16(al,v1,acc1,0,0,0);
    acc2=__builtin_amdgcn_mfma_f32_16x16x32_bf16(ah,v2,acc2,0,0,0);
    acc2=__builtin_amdgcn_mfma_f32_16x16x32_bf16(al,v2,acc2,0,0,0);
    acc3=__builtin_amdgcn_mfma_f32_16x16x32_bf16(ah,v3,acc3,0,0,0);
    acc3=__builtin_amdgcn_mfma_f32_16x16x32_bf16(al,v3,acc3,0,0,0);
  }
  {
    int r0 = l4*4;                       // ALL 64 lanes: rows 0-15
    #pragma unroll
    for (int q=0;q<4;q++){
      part[(r0+q)*PSX + w*64 +  0 + l15] = acc0[q];
      part[(r0+q)*PSX + w*64 + 16 + l15] = acc1[q];
      part[(r0+q)*PSX + w*64 + 32 + l15] = acc2[q];
      part[(r0+q)*PSX + w*64 + 48 + l15] = acc3[q];
    }
  }
  __syncthreads();
  // ---- layer1 cell + store states; restage A as [c0|h0|c1|h1] for q
  float eb4=exb[1024+j], eb5=exb[1280+j], eb6=exb[1536+j], eb7=exb[1792+j];
  #pragma unroll
  for (int q=0;q<4;q++){
    int r = 4*q + rp;
    int grow = row0 + r;
    bool g = grow < ROWS;
    float a0 = eb4 + part[r*PSX + j];
    float a1 = eb5 + part[r*PSX + 256 + j];
    float a2 = eb6 + part[r*PSX + 512 + j];
    float a3 = eb7 + part[r*PSX + 768 + j];
    float cp = g ? c1pg[grow*256 + j] : 0.f;
    float ii=sigf(a0), ff=sigf(a1), gg=tanh_fast(a2), oo=sigf(a3);
    float cn = ff*cp + ii*gg;
    float hn = oo*tanh_fast(cn);
    if (g){
      int o = grow*256 + j;
      c0o[o]=c0s[q]; h0o[o]=h0s[q]; c1o[o]=cn; h1o[o]=hn;
    }
    u16 hi;
    hi = f2bf(c0s[q]); Ah[r*RSX +       j] = hi; Al[r*RSX +       j] = f2bf(c0s[q]-bf2f(hi));
    hi = f2bf(h0s[q]); Ah[r*RSX + 256 + j] = hi; Al[r*RSX + 256 + j] = f2bf(h0s[q]-bf2f(hi));
    hi = f2bf(cn);     Ah[r*RSX + 512 + j] = hi; Al[r*RSX + 512 + j] = f2bf(cn-bf2f(hi));
    hi = f2bf(hn);     Ah[r*RSX + 768 + j] = hi; Al[r*RSX + 768 + j] = f2bf(hn-bf2f(hi));
  }
  __syncthreads();
  // ---- q matvec: K=1024 (32 ksteps), N=256 (tile = wave)
  f32x4 accq = {0,0,0,0};
  #pragma unroll 4
  for (int ks=0; ks<32; ks++){
    bfv8 ah = *(const bfv8*)&Ah[aoff + ks*32];
    bfv8 al = *(const bfv8*)&Al[aoff + ks*32];
    uint4 b = WKm[(w*32 + ks)*64 + lane];
    bfv8 v = __builtin_bit_cast(bfv8, b);
    accq = __builtin_amdgcn_mfma_f32_16x16x32_bf16(ah, v, accq, 0,0,0);
    accq = __builtin_amdgcn_mfma_f32_16x16x32_bf16(al, v, accq, 0,0,0);
  }
  {
    int r0 = l4*4;
    #pragma unroll
    for (int q=0;q<4;q++)
      part[(r0+q)*260 + w*16 + l15] = accq[q];
  }
  __syncthreads();
  float bkv = bk[j];
  #pragma unroll
  for (int q=0;q<4;q++){
    int r = 4*q + rp;
    int grow = row0 + r;
    if (grow < ROWS) qb[grow*256 + j] = part[r*260 + j] + bkv;
  }
}

// ---------------- K6: out = h_exit @ wo + bo -----------------------------
__global__ __launch_bounds__(256) void k_out(
    const float* __restrict__ h1f, const int* __restrict__ exitIdx,
    const float* __restrict__ wo, const float* __restrict__ bo, float* __restrict__ out){
  __shared__ float hv[8][256];
  int tid = threadIdx.x;
  for (int i = tid; i < 2048; i += 256){
    int b = i >> 8, k = i & 255;
    hv[b][k] = h1f[(b*81 + exitIdx[b])*256 + k];
  }
  __syncthreads();
  int v = blockIdx.x*256 + tid;
  if (v >= 30000) return;
  float acc[8];
  #pragma unroll
  for (int b=0;b<8;b++) acc[b] = bo[v];
  for (int k=0;k<256;k++){
    float w = wo[k*30000 + v];
    #pragma unroll
    for (int b=0;b<8;b++) acc[b] = fmaf(hv[b][k], w, acc[b]);
  }
  #pragma unroll
  for (int b=0;b<8;b++) out[b*30000+v] = acc[b];
}

// ---------------- launch --------------------------------------------------
extern "C" void kernel_launch(void* const* d_in, const int* in_sizes, int n_in,
                              void* d_out, int out_size, void* d_ws, size_t ws_size,
                              hipStream_t stream){
  (void)in_sizes; (void)n_in; (void)out_size;
  const float* ne    = (const float*)d_in[0];
  const int*   exitI = (const int*)d_in[10];
  const float* stWx  = (const float*)d_in[12];
  const float* stb   = (const float*)d_in[14];
  const float* skWx  = (const float*)d_in[15];
  const float* skWh  = (const float*)d_in[16];
  const float* skb   = (const float*)d_in[17];
  const float* lnS   = (const float*)d_in[18];
  const float* lnB   = (const float*)d_in[19];
  const float* exWx  = (const float*)d_in[20];
  const float* exWh  = (const float*)d_in[21];
  const float* exb   = (const float*)d_in[22];
  const float* wk    = (const float*)d_in[23];
  const float* bk    = (const float*)d_in[24];
  const float* wsm   = (const float*)d_in[25];
  const float* bs    = (const float*)d_in[26];
  const float* w1    = (const float*)d_in[27];
  const float* wo    = (const float*)d_in[29];
  const float* bo    = (const float*)d_in[30];
  float* out = (float*)d_out;

  char* w = (char*)d_ws;
  size_t off = 0;
  auto alloc = [&](size_t bytes)->char*{
    char* p = w + off; off += (bytes + 255) & ~size_t(255); return p;
  };
  float4* X0   = (float4*)alloc((size_t)640*256*16);
  u32* W0m     = (u32*)alloc((size_t)131072*4);          // skip L0, K=256
  u32* W1m     = (u32*)alloc((size_t)262144*4);          // skip L1, K=512
  u32* WAm     = (u32*)alloc((size_t)262144*4);          // ex L0, K=512
  u32* WBm     = (u32*)alloc((size_t)262144*4);          // ex L1, K=512
  u32* WKm     = (u32*)alloc((size_t)131072*4);          // wk, K=1024 N=256
  u32* WSm     = (u32*)alloc((size_t)32768*4);           // ws, K=256 N=256
  float* skip  = (float*)alloc((size_t)8*81*81*256*4);   // fp32
  u16* keys    = (u16*)alloc((size_t)8*81*81*256*2);     // bf16
  float* tb    = (float*)alloc((size_t)ROWS*81*4);
  float* p0    = (float*)alloc(ROWS*4);
  float* p1    = (float*)alloc(ROWS*4);
  float* stA   = (float*)alloc((size_t)4*ROWS*256*4);
  float* stB   = (float*)alloc((size_t)4*ROWS*256*4);
  float* xinb  = (float*)alloc((size_t)ROWS*256*4);
  float* h0pb  = (float*)alloc((size_t)ROWS*256*4);
  float* h1pb  = (float*)alloc((size_t)ROWS*256*4);
  float* c0pb  = (float*)alloc((size_t)ROWS*256*4);
  float* c1pb  = (float*)alloc((size_t)ROWS*256*4);
  float* qb    = (float*)alloc((size_t)ROWS*256*4);
  if (off > ws_size) return;   // workspace too small — surfaces as absmax fail

  const size_t ST = (size_t)ROWS*256;
  float *A_c0=stA, *A_h0=stA+ST, *A_c1=stA+2*ST, *A_h1=stA+3*ST;
  float *B_c0=stB, *B_h0=stB+ST, *B_c1=stB+2*ST, *B_h1=stB+3*ST;

  hipMemsetAsync(skip, 0, (size_t)8*81*81*256*4, stream);
  hipMemsetAsync(stA, 0, (size_t)4*ROWS*256*4, stream);
  hipMemsetAsync(stB, 0, (size_t)4*ROWS*256*4, stream);
  k_init_p<<<3,256,0,stream>>>(p0);

  pack_mfma<<<512, 256, 0, stream>>>(skWh, skWh, W0m, 256);                        // Wh0
  pack_mfma<<<1024,256, 0, stream>>>(skWx+256*1024, skWh+256*1024, W1m, 512);      // [Wx1;Wh1]
  pack_mfma<<<1024,256, 0, stream>>>(exWx, exWh, WAm, 512);                        // [exWx0;exWh0]
  pack_mfma<<<1024,256, 0, stream>>>(exWx+256*1024, exWh+256*1024, WBm, 512);      // [exWx1;exWh1]
  pack_w<<<512, 256, 0, stream>>>(wk, WKm, 1024, 16);
  pack_w<<<128, 256, 0, stream>>>(wsm, WSm, 256, 16);

  k_stmt_x0<<<320, 512, 0, stream>>>(ne, stWx, stb, skWx, skb, X0);
  k_skip_chains<<<80, 1024, 0, stream>>>(X0, (const uint4*)W0m, (const uint4*)W1m,
                                         skb, lnS, lnB, skip);
  k_keys<<<(KROWS+15)/16, 1024, 0, stream>>>(skip, (const uint4*)WSm, bs, keys);

  float* pc = p0; float* pn = p1;
  for (int s=0; s<8; s++){
    float *ic0,*ih0,*ic1,*ih1,*oc0,*oh0,*oc1,*oh1;
    if ((s & 1) == 0){ ic0=A_c0; ih0=A_h0; ic1=A_c1; ih1=A_h1; oc0=B_c0; oh0=B_h0; oc1=B_c1; oh1=B_h1; }
    else             { ic0=B_c0; ih0=B_h0; ic1=B_c1; ih1=B_h1; oc0=A_c0; oh0=A_h0; oc1=A_c1; oh1=A_h1; }
    int mode = (s==0) ? 0 : ((s==7) ? 2 : 1);
    k_attn<<<648, 256, 0, stream>>>(qb, keys, w1, pc, tb, mode);
    k_gather<<<648, 256, 0, stream>>>(tb, skip, ic0, ih0, ic1, ih1,
                                      xinb, h0pb, h1pb, c0pb, c1pb, pn);
    k_exlstm<<<41, 1024, 0, stream>>>(xinb, h0pb, h1pb, c0pb, c1pb,
                                      (const uint4*)WAm, (const uint4*)WBm,
                                      (const uint4*)WKm, exb, bk,
                                      oc0, oh0, oc1, oh1, qb);
    float* tmp = pc; pc = pn; pn = tmp;
  }
  // final states are in buffer A (step 7 writes A)
  k_out<<<(30000+255)/256, 256, 0, stream>>>(A_h1, exitI, wo, bo, out);
}